// Round 13
// baseline (177.208 us; speedup 1.0000x reference)
//
#include <hip/hip_runtime.h>
#include <hip/hip_bf16.h>
#include <stdint.h>

// ---------------------------------------------------------------------------
// MultiHeadAttention (no head split): out = softmax_causal((xWq)(xWk)^T/32)(xWv) Wo
// B=4, T=2048, C=1024, fp32 in/out, bf16 MFMA compute.
// Round 13: r12's proven 2-barrier dbuf schedule applied to QK (128x256,
//   288 live WGs, ~2/CU) and oproj (128x128, 512 WGs, fully packed round).
// QKV: r12 qkv256 (128x256/BK32, 48KiB, 2 WGs/CU). PV: paired-triangular.
// Zero-conflict swizzle throughout.
// ---------------------------------------------------------------------------

typedef __attribute__((ext_vector_type(8))) __bf16 bf16x8;
typedef __attribute__((ext_vector_type(4))) __bf16 bf16x4;
typedef __attribute__((ext_vector_type(4))) float f32x4;

#define MFMA16(A, B, C) __builtin_amdgcn_mfma_f32_16x16x32_bf16(A, B, C, 0, 0, 0)
#define BAR() asm volatile("s_barrier" ::: "memory")

#define T_SEQ 2048
#define D_MOD 1024

static __device__ __forceinline__ void gload_lds16(const void* g, void* l) {
  __builtin_amdgcn_global_load_lds(
      (const __attribute__((address_space(1))) void*)g,
      (__attribute__((address_space(3))) void*)l, 16, 0, 0);
}

// ------------------------- elementwise fp32 -> bf16 ------------------------
__global__ void cvt_bf16_kernel(const float* __restrict__ in,
                                __bf16* __restrict__ out, int n8) {
  int i = blockIdx.x * blockDim.x + threadIdx.x;
  if (i < n8) {
    const float4* p = (const float4*)(in + (size_t)i * 8);
    float4 a = p[0], b = p[1];
    bf16x8 o;
    o[0] = (__bf16)a.x; o[1] = (__bf16)a.y; o[2] = (__bf16)a.z; o[3] = (__bf16)a.w;
    o[4] = (__bf16)b.x; o[5] = (__bf16)b.y; o[6] = (__bf16)b.z; o[7] = (__bf16)b.w;
    *(bf16x8*)(out + (size_t)i * 8) = o;
  }
}

// ---------- all four W (K x N fp32) -> Wt (N x K bf16), one launch ---------
__global__ void transpose_cvt4_kernel(const float* __restrict__ Wq,
                                      const float* __restrict__ Wk,
                                      const float* __restrict__ Wv,
                                      const float* __restrict__ Wo,
                                      __bf16* __restrict__ Wqkvt,
                                      __bf16* __restrict__ Wot) {
  __shared__ float tile[32][33];
  const int z = blockIdx.z;
  const float* W = (z == 0) ? Wq : (z == 1) ? Wk : (z == 2) ? Wv : Wo;
  __bf16* Wt = (z < 3) ? (Wqkvt + (size_t)z * 1024 * 1024) : Wot;
  int tx = threadIdx.x, ty = threadIdx.y;
  int bx = blockIdx.x * 32, by = blockIdx.y * 32;
#pragma unroll
  for (int i = 0; i < 4; i++)
    tile[ty + 8 * i][tx] = W[(size_t)(by + ty + 8 * i) * D_MOD + bx + tx];
  __syncthreads();
#pragma unroll
  for (int i = 0; i < 4; i++)
    Wt[(size_t)(bx + ty + 8 * i) * D_MOD + by + tx] = (__bf16)tile[tx][ty + 8 * i];
}

// ======= QKV: 128x256 / BK=32 dbuf GEMM, 48KiB LDS, 2 WGs/CU, 768 WGs ======
// (r12, proven). Per tile: {8 ds_read; lgkmcnt(0); BAR}
//                          {stage t+2 in-place; 16 MFMA; vmcnt(3); BAR}
__global__ __launch_bounds__(512, 2) void qkv256_kernel(
    const __bf16* __restrict__ A, const __bf16* __restrict__ Bt,
    const float* __restrict__ bq, const float* __restrict__ bk,
    const float* __restrict__ bv, __bf16* __restrict__ Qo,
    __bf16* __restrict__ Ko, __bf16* __restrict__ Vto) {
  constexpr int NT = 32;  // K = 1024, BK = 32
  __shared__ __align__(16) char lds[49152];
#define ABUF(p) (lds + (p) * 8192)
#define BBUF(p) (lds + 16384 + (p) * 16384)

  const int tid = threadIdx.x;
  const int w = tid >> 6, l = tid & 63;
  const int wr = w >> 2, wc = w & 3;  // 2M x 4N
  const int cpx = gridDim.x >> 3;     // 768 % 8 == 0, bijective XCD swizzle
  const int swz = ((int)blockIdx.x & 7) * cpx + ((int)blockIdx.x >> 3);
  const int bm = (swz / 12) * 128;    // 64 m-tiles
  const int bn = (swz % 12) * 256;    // 12 n-tiles

  const int cswz = (l & 3) ^ ((l >> 3) & 3);           // staging src chunk
  const int rlo = l & 15;                              // frag row within 16
  const int xsw = (((l >> 4) ^ ((l >> 1) & 3)) << 4);  // frag read chunk
  const int srow = w * 16 + (l >> 2);                  // staged row (0..127)

#define STAGE_A(t, p)                                                  \
  {                                                                    \
    const __bf16* g = A + (size_t)(bm + srow) * 1024 + (t) * 32 +      \
                      cswz * 8;                                        \
    gload_lds16(g, ABUF(p) + w * 1024 + l * 16);                       \
  }
#define STAGE_B(t, p)                                                  \
  {                                                                    \
    const __bf16* g0 = Bt + (size_t)(bn + srow) * 1024 + (t) * 32 +    \
                       cswz * 8;                                       \
    char* d = BBUF(p) + w * 1024 + l * 16;                             \
    gload_lds16(g0, d);                                                \
    gload_lds16(g0 + (size_t)128 * 1024, d + 8192);                    \
  }

  f32x4 acc[4][4] = {};
  STAGE_A(0, 0); STAGE_B(0, 0);
  STAGE_A(1, 1); STAGE_B(1, 1);
  asm volatile("s_waitcnt vmcnt(3)" ::: "memory");  // tile 0's 3 landed
  BAR();

  for (int t = 0; t < NT; ++t) {
    const int p = t & 1;
    bf16x8 af[4], bf[4];
#pragma unroll
    for (int i = 0; i < 4; i++)
      af[i] = *(const bf16x8*)(ABUF(p) + (wr * 64 + i * 16 + rlo) * 64 + xsw);
#pragma unroll
    for (int n = 0; n < 4; n++)
      bf[n] = *(const bf16x8*)(BBUF(p) + (wc * 64 + n * 16 + rlo) * 64 + xsw);
    asm volatile("s_waitcnt lgkmcnt(0)" ::: "memory");  // reads retired
    BAR();  // all waves done reading buf p -> in-place restage safe
    if (t + 2 < NT) {
      STAGE_A(t + 2, p);
      STAGE_B(t + 2, p);
    }
    __builtin_amdgcn_s_setprio(1);
#pragma unroll
    for (int i = 0; i < 4; i++)
#pragma unroll
      for (int n = 0; n < 4; n++)
        acc[i][n] = MFMA16(af[i], bf[n], acc[i][n]);
    __builtin_amdgcn_s_setprio(0);
    if (t + 2 < NT) asm volatile("s_waitcnt vmcnt(3)" ::: "memory");
    else asm volatile("s_waitcnt vmcnt(0)" ::: "memory");
    BAR();
  }

  const int l4 = (l >> 4) * 4;
  const int seg = bn >> 10;
  const int bnl = bn & 1023;
  if (seg < 2) {
    const float* bs = seg ? bk : bq;
    __bf16* os = seg ? Ko : Qo;
#pragma unroll
    for (int n4 = 0; n4 < 4; n4++) {
      int col = bnl + wc * 64 + n4 * 16 + rlo;
      float bvv = bs[col];
#pragma unroll
      for (int m = 0; m < 4; m++) {
        int rowb = bm + wr * 64 + m * 16 + l4;
#pragma unroll
        for (int r = 0; r < 4; r++)
          os[(size_t)(rowb + r) * D_MOD + col] = (__bf16)(acc[m][n4][r] + bvv);
      }
    }
  } else {
#pragma unroll
    for (int n4 = 0; n4 < 4; n4++) {
      int lcol = bnl + wc * 64 + n4 * 16 + rlo;
      float bvv = bv[lcol];
#pragma unroll
      for (int m = 0; m < 4; m++) {
        int rowb = bm + wr * 64 + m * 16 + l4;  // mult of 4
        int zz = rowb >> 11, tt = rowb & 2047;
        bf16x4 pk;
#pragma unroll
        for (int r = 0; r < 4; r++) pk[r] = (__bf16)(acc[m][n4][r] + bvv);
        *(bf16x4*)(Vto + (size_t)zz * (D_MOD * T_SEQ) + (size_t)lcol * T_SEQ +
                   tt) = pk;
      }
    }
  }
#undef ABUF
#undef BBUF
#undef STAGE_A
#undef STAGE_B
}

// ====== QK: 128x256 / BK=32 dbuf (r12 schedule), causal f32 epilogue =======
// Live tiles only: per batch, m-tile ti (0..15) has n-tiles tj = 0..ti/2
// -> 72 WGs/batch, grid (72, B). Epilogue: *1/32, col>row -> -1e30, ldc 2048.
__global__ __launch_bounds__(512, 2) void qk128_kernel(
    const __bf16* __restrict__ Q, const __bf16* __restrict__ K,
    float* __restrict__ So, size_t bsA, size_t bsB, size_t bsC) {
  constexpr int NT = 32;
  __shared__ __align__(16) char lds[49152];
#define ABUF(p) (lds + (p) * 8192)
#define BBUF(p) (lds + 16384 + (p) * 16384)

  const int tid = threadIdx.x;
  const int w = tid >> 6, l = tid & 63;
  const int wr = w >> 2, wc = w & 3;
  // triangular decode: x -> (ti, tj) with tj <= ti/2
  int x = (int)blockIdx.x, ti = 0;
  for (;;) {
    int cnt = (ti >> 1) + 1;
    if (x < cnt) break;
    x -= cnt;
    ++ti;
  }
  const int tj = x;
  const int bm = ti * 128, bn = tj * 256;
  const int z = blockIdx.y;
  const __bf16* A = Q + (size_t)z * bsA;
  const __bf16* Bt = K + (size_t)z * bsB;

  const int cswz = (l & 3) ^ ((l >> 3) & 3);
  const int rlo = l & 15;
  const int xsw = (((l >> 4) ^ ((l >> 1) & 3)) << 4);
  const int srow = w * 16 + (l >> 2);

#define STAGE_A(t, p)                                                  \
  {                                                                    \
    const __bf16* g = A + (size_t)(bm + srow) * 1024 + (t) * 32 +      \
                      cswz * 8;                                        \
    gload_lds16(g, ABUF(p) + w * 1024 + l * 16);                       \
  }
#define STAGE_B(t, p)                                                  \
  {                                                                    \
    const __bf16* g0 = Bt + (size_t)(bn + srow) * 1024 + (t) * 32 +    \
                       cswz * 8;                                       \
    char* d = BBUF(p) + w * 1024 + l * 16;                             \
    gload_lds16(g0, d);                                                \
    gload_lds16(g0 + (size_t)128 * 1024, d + 8192);                    \
  }

  f32x4 acc[4][4] = {};
  STAGE_A(0, 0); STAGE_B(0, 0);
  STAGE_A(1, 1); STAGE_B(1, 1);
  asm volatile("s_waitcnt vmcnt(3)" ::: "memory");
  BAR();

  for (int t = 0; t < NT; ++t) {
    const int p = t & 1;
    bf16x8 af[4], bf[4];
#pragma unroll
    for (int i = 0; i < 4; i++)
      af[i] = *(const bf16x8*)(ABUF(p) + (wr * 64 + i * 16 + rlo) * 64 + xsw);
#pragma unroll
    for (int n = 0; n < 4; n++)
      bf[n] = *(const bf16x8*)(BBUF(p) + (wc * 64 + n * 16 + rlo) * 64 + xsw);
    asm volatile("s_waitcnt lgkmcnt(0)" ::: "memory");
    BAR();
    if (t + 2 < NT) {
      STAGE_A(t + 2, p);
      STAGE_B(t + 2, p);
    }
    __builtin_amdgcn_s_setprio(1);
#pragma unroll
    for (int i = 0; i < 4; i++)
#pragma unroll
      for (int n = 0; n < 4; n++)
        acc[i][n] = MFMA16(af[i], bf[n], acc[i][n]);
    __builtin_amdgcn_s_setprio(0);
    if (t + 2 < NT) asm volatile("s_waitcnt vmcnt(3)" ::: "memory");
    else asm volatile("s_waitcnt vmcnt(0)" ::: "memory");
    BAR();
  }

  float* os = So + (size_t)z * bsC;
  const int l4 = (l >> 4) * 4;
#pragma unroll
  for (int n4 = 0; n4 < 4; n4++) {
    int col = bn + wc * 64 + n4 * 16 + rlo;
#pragma unroll
    for (int m = 0; m < 4; m++) {
      int rowb = bm + wr * 64 + m * 16 + l4;
#pragma unroll
      for (int r = 0; r < 4; r++) {
        int row = rowb + r;
        float v = acc[m][n4][r] * 0.03125f;  // 1/sqrt(1024)
        if (col > row) v = -1e30f;
        os[(size_t)row * T_SEQ + col] = v;
      }
    }
  }
#undef ABUF
#undef BBUF
#undef STAGE_A
#undef STAGE_B
}

// ====== oproj: 128x128 / BK=32 dbuf (r12 schedule), f32 + bias, 512 WGs ====
__global__ __launch_bounds__(512, 2) void oproj128_kernel(
    const __bf16* __restrict__ A, const __bf16* __restrict__ Bt,
    const float* __restrict__ b0, float* __restrict__ o0) {
  constexpr int NT = 32;
  __shared__ __align__(16) char lds[32768];
#define ABUF(p) (lds + (p) * 8192)
#define BBUF(p) (lds + 16384 + (p) * 8192)

  const int tid = threadIdx.x;
  const int w = tid >> 6, l = tid & 63;
  const int wr = w >> 2, wc = w & 3;  // wave tile 64x32
  const int cpx = gridDim.x >> 3;     // 512 % 8 == 0
  const int swz = ((int)blockIdx.x & 7) * cpx + ((int)blockIdx.x >> 3);
  const int bm = (swz >> 3) * 128;    // 64 m-tiles
  const int bn = (swz & 7) * 128;     // 8 n-tiles

  const int cswz = (l & 3) ^ ((l >> 3) & 3);
  const int rlo = l & 15;
  const int xsw = (((l >> 4) ^ ((l >> 1) & 3)) << 4);
  const int srow = w * 16 + (l >> 2);

#define STAGE_A(t, p)                                                  \
  {                                                                    \
    const __bf16* g = A + (size_t)(bm + srow) * 1024 + (t) * 32 +      \
                      cswz * 8;                                        \
    gload_lds16(g, ABUF(p) + w * 1024 + l * 16);                       \
  }
#define STAGE_B(t, p)                                                  \
  {                                                                    \
    const __bf16* g = Bt + (size_t)(bn + srow) * 1024 + (t) * 32 +     \
                      cswz * 8;                                        \
    gload_lds16(g, BBUF(p) + w * 1024 + l * 16);                       \
  }

  f32x4 acc[4][2] = {};
  STAGE_A(0, 0); STAGE_B(0, 0);
  STAGE_A(1, 1); STAGE_B(1, 1);
  asm volatile("s_waitcnt vmcnt(2)" ::: "memory");  // tile 0's 2 landed
  BAR();

  for (int t = 0; t < NT; ++t) {
    const int p = t & 1;
    bf16x8 af[4], bf[2];
#pragma unroll
    for (int i = 0; i < 4; i++)
      af[i] = *(const bf16x8*)(ABUF(p) + (wr * 64 + i * 16 + rlo) * 64 + xsw);
#pragma unroll
    for (int n = 0; n < 2; n++)
      bf[n] = *(const bf16x8*)(BBUF(p) + (wc * 32 + n * 16 + rlo) * 64 + xsw);
    asm volatile("s_waitcnt lgkmcnt(0)" ::: "memory");
    BAR();
    if (t + 2 < NT) {
      STAGE_A(t + 2, p);
      STAGE_B(t + 2, p);
    }
    __builtin_amdgcn_s_setprio(1);
#pragma unroll
    for (int i = 0; i < 4; i++)
#pragma unroll
      for (int n = 0; n < 2; n++)
        acc[i][n] = MFMA16(af[i], bf[n], acc[i][n]);
    __builtin_amdgcn_s_setprio(0);
    if (t + 2 < NT) asm volatile("s_waitcnt vmcnt(2)" ::: "memory");
    else asm volatile("s_waitcnt vmcnt(0)" ::: "memory");
    BAR();
  }

  const int l4 = (l >> 4) * 4;
#pragma unroll
  for (int n = 0; n < 2; n++) {
    int col = bn + wc * 32 + n * 16 + rlo;
    float bvv = b0[col];
#pragma unroll
    for (int m = 0; m < 4; m++) {
      int rowb = bm + wr * 64 + m * 16 + l4;
#pragma unroll
      for (int r = 0; r < 4; r++)
        o0[(size_t)(rowb + r) * D_MOD + col] = acc[m][n][r] + bvv;
    }
  }
#undef ABUF
#undef BBUF
#undef STAGE_A
#undef STAGE_B
}

// ======== PV: 128x128 paired-triangular GEMM (34 BK-steps/WG, 1 round) =====
__global__ __launch_bounds__(512, 2) void pv_kernel(
    const __bf16* __restrict__ Ap, const __bf16* __restrict__ Btp,
    __bf16* __restrict__ Op, size_t bsA, size_t bsB, size_t bsC) {
  __shared__ __align__(16) char lds[98304];
#define ABUF(p3) (lds + (p3) * 16384)
#define BBUF(p3) (lds + 49152 + (p3) * 16384)

  const int tid = threadIdx.x;
  const int w = tid >> 6, l = tid & 63;
  const int wr = w >> 2, wc = w & 3;  // 2M x 4N; wave tile 64x32
  const int pid = (int)blockIdx.x >> 3;
  const int bn = ((int)blockIdx.x & 7) * 128;
  const int z = blockIdx.z;
  const __bf16* A = Ap + (size_t)z * bsA;
  const __bf16* Bt = Btp + (size_t)z * bsB;
  __bf16* O = Op + (size_t)z * bsC;

  const int grow = w * 16 + (l >> 2);
  const int cswz = (l & 3) ^ ((l >> 3) & 3);
  const int rlo = l & 15;
  const int xsw = (((l >> 4) ^ ((l >> 1) & 3)) << 4);

#define PSTAGE_A(t, p3)                                                      \
  {                                                                          \
    const __bf16* g = A + (size_t)(bm + grow) * 4096 + (t) * 64 + cswz * 8;  \
    char* d = ABUF(p3) + w * 1024 + l * 16;                                  \
    gload_lds16(g, d);                                                       \
    gload_lds16(g + 32, d + 8192);                                           \
  }
#define PSTAGE_B(t, p3)                                                      \
  {                                                                          \
    const __bf16* g = Bt + (size_t)(bn + grow) * 2048 + (t) * 64 + cswz * 8; \
    char* d = BBUF(p3) + w * 1024 + l * 16;                                  \
    gload_lds16(g, d);                                                       \
    gload_lds16(g + 32, d + 8192);                                           \
  }
#define PLDA(p3, i, kk)                                           \
  (*(const bf16x8*)(ABUF(p3) + (kk) * 8192 +                      \
                    (wr * 64 + (i) * 16 + rlo) * 64 + xsw))
#define PLDB(p3, n, kk)                                           \
  (*(const bf16x8*)(BBUF(p3) + (kk) * 8192 +                      \
                    (wc * 32 + (n) * 16 + rlo) * 64 + xsw))

#pragma unroll
  for (int seg = 0; seg < 2; ++seg) {
    const int i = seg ? (15 - pid) : pid;
    const int bm = i * 128;
    const int NT = (i + 1) * 2;  // BK=64 steps over K=(i+1)*128
    f32x4 acc[4][2] = {};

    PSTAGE_A(0, 0); PSTAGE_B(0, 0);
    if (NT > 1) { PSTAGE_A(1, 1); PSTAGE_B(1, 1); }
    asm volatile("s_waitcnt vmcnt(4)" ::: "memory");
    BAR();

    int p = 0, pn2 = 2;
    for (int t = 0; t < NT; ++t) {
      bf16x8 af[4][2], bfv[2][2];
#pragma unroll
      for (int m = 0; m < 4; m++) {
        af[m][0] = PLDA(p, m, 0);
        af[m][1] = PLDA(p, m, 1);
      }
#pragma unroll
      for (int n = 0; n < 2; n++) {
        bfv[n][0] = PLDB(p, n, 0);
        bfv[n][1] = PLDB(p, n, 1);
      }
      if (t + 2 < NT) { PSTAGE_A(t + 2, pn2); PSTAGE_B(t + 2, pn2); }
      BAR();
      __builtin_amdgcn_s_setprio(1);
#pragma unroll
      for (int m = 0; m < 4; m++)
#pragma unroll
        for (int n = 0; n < 2; n++) {
          acc[m][n] = MFMA16(af[m][0], bfv[n][0], acc[m][n]);
          acc[m][n] = MFMA16(af[m][1], bfv[n][1], acc[m][n]);
        }
      __builtin_amdgcn_s_setprio(0);
      if (t + 2 < NT) asm volatile("s_waitcnt vmcnt(4)" ::: "memory");
      else asm volatile("s_waitcnt vmcnt(0)" ::: "memory");
      BAR();
      p = (p + 1 == 3) ? 0 : p + 1;
      pn2 = (pn2 + 1 == 3) ? 0 : pn2 + 1;
    }

#pragma unroll
    for (int n = 0; n < 2; n++) {
      int col = bn + wc * 32 + n * 16 + rlo;
#pragma unroll
      for (int m = 0; m < 4; m++) {
        int rowb = bm + wr * 64 + m * 16 + (l >> 4) * 4;
#pragma unroll
        for (int r = 0; r < 4; r++)
          O[(size_t)(rowb + r) * D_MOD + col] = (__bf16)acc[m][n][r];
      }
    }
    BAR();  // LDS safe before next segment restage
  }
#undef ABUF
#undef BBUF
#undef PSTAGE_A
#undef PSTAGE_B
#undef PLDA
#undef PLDB
}

// ----------------------- row softmax, P bf16 in-place ----------------------
__global__ __launch_bounds__(256) void softmax_kernel(float* __restrict__ S,
                                                      size_t bstride) {
  const int t = blockIdx.x, b = blockIdx.y;
  float* Srow = S + (size_t)b * bstride + (size_t)t * T_SEQ;
  __bf16* Prow = (__bf16*)Srow;
  const int L = ((t + 1) + 127) & ~127;
  const int tid = threadIdx.x;
  const int base = tid * 8;
  const bool act = base < L;
  float v[8];
  float m = -1e30f;
  if (act) {
    float4 a = *(const float4*)(Srow + base);
    float4 c = *(const float4*)(Srow + base + 4);
    v[0] = a.x; v[1] = a.y; v[2] = a.z; v[3] = a.w;
    v[4] = c.x; v[5] = c.y; v[6] = c.z; v[7] = c.w;
#pragma unroll
    for (int j = 0; j < 8; j++) m = fmaxf(m, v[j]);
  }
#pragma unroll
  for (int off = 1; off < 64; off <<= 1) m = fmaxf(m, __shfl_xor(m, off));
  __shared__ float redm[4], reds[4];
  const int wave = tid >> 6, lane = tid & 63;
  if (lane == 0) redm[wave] = m;
  __syncthreads();
  m = fmaxf(fmaxf(redm[0], redm[1]), fmaxf(redm[2], redm[3]));
  float p[8];
  float s = 0.f;
  if (act) {
#pragma unroll
    for (int j = 0; j < 8; j++) {
      p[j] = __expf(v[j] - m);
      s += p[j];
    }
  }
#pragma unroll
  for (int off = 1; off < 64; off <<= 1) s += __shfl_xor(s, off);
  if (lane == 0) reds[wave] = s;
  __syncthreads();  // fences: reads done before in-place bf16 writes
  const float inv = 1.0f / (reds[0] + reds[1] + reds[2] + reds[3]);
  if (act) {
    bf16x8 o;
#pragma unroll
    for (int j = 0; j < 8; j++) o[j] = (__bf16)(p[j] * inv);
    *(bf16x8*)(Prow + base) = o;
  }
}

// ---------------------------------------------------------------------------
extern "C" void kernel_launch(void* const* d_in, const int* in_sizes, int n_in,
                              void* d_out, int out_size, void* d_ws,
                              size_t ws_size, hipStream_t stream) {
  const float* x = (const float*)d_in[0];
  const float* Wq = (const float*)d_in[1];
  const float* bq = (const float*)d_in[2];
  const float* Wk = (const float*)d_in[3];
  const float* bk = (const float*)d_in[4];
  const float* Wv = (const float*)d_in[5];
  const float* bv = (const float*)d_in[6];
  const float* Wo = (const float*)d_in[7];
  const float* bo = (const float*)d_in[8];

  char* ws = (char*)d_ws;
  const size_t MB = 1u << 20;
  const size_t TC = (size_t)T_SEQ * D_MOD;  // 2M elems / batch
  const size_t TT = (size_t)T_SEQ * T_SEQ;  // 4M elems / batch
  __bf16* xb    = (__bf16*)(ws);            // [0,16) MB ; dead after QKV
  __bf16* Wqkvt = (__bf16*)(ws + 16 * MB);  // [16,22)  3072x1024
  __bf16* Wot   = (__bf16*)(ws + 22 * MB);  // [22,24)
  __bf16* Qb    = (__bf16*)(ws + 24 * MB);  // [24,40) ; later AO
  __bf16* Kb    = (__bf16*)(ws + 40 * MB);  // [40,56)
  __bf16* Vtb   = (__bf16*)(ws + 56 * MB);  // [56,72)  V^T direct from QKV

  // 1) x -> bf16
  cvt_bf16_kernel<<<4096, 256, 0, stream>>>(x, xb, 8192 * D_MOD / 8);
  // 2) weight transposes (one dispatch)
  transpose_cvt4_kernel<<<dim3(32, 32, 4), dim3(32, 8), 0, stream>>>(
      Wq, Wk, Wv, Wo, Wqkvt, Wot);
  // 3) fused QKV projection (48KiB LDS, 2 WGs/CU); V written transposed
  qkv256_kernel<<<768, 512, 0, stream>>>(xb, Wqkvt, bq, bk, bv, Qb, Kb, Vtb);

  const bool batched = ws_size >= 137 * MB;
  if (batched) {
    float* S = (float*)(ws + 72 * MB);  // [72,136) fp32, 4 batches
    __bf16* AO = Qb;                    // Q dead after QK
    // 4) S = QK^T * scale, causal: 72 live 128x256 tiles per batch
    qk128_kernel<<<dim3(72, 4), 512, 0, stream>>>(Qb, Kb, S, TC, TC, TT);
    // 5) row softmax, P bf16 in-place (row stride 4096 bf16)
    softmax_kernel<<<dim3(T_SEQ, 4), 256, 0, stream>>>(S, TT);
    // 6) O = P V, paired triangular 128x128 tiles (1 balanced round)
    pv_kernel<<<dim3(64, 1, 4), 512, 0, stream>>>((const __bf16*)S, Vtb, AO,
                                                  TT * 2, TC, TC);
    // 7) out projection (f32 out), 128x128 tiles, 512 WGs fully packed
    oproj128_kernel<<<512, 512, 0, stream>>>(AO, Wot, bo, (float*)d_out);
  } else {
    // per-batch fallback: S reuses xb region (dead after QKV), AO over Qb
    float* S = (float*)(ws);
    __bf16* AO = Qb;
    for (int b = 0; b < 4; ++b) {
      qk128_kernel<<<dim3(72, 1), 512, 0, stream>>>(Qb + b * TC, Kb + b * TC,
                                                    S, 0, 0, 0);
      softmax_kernel<<<dim3(T_SEQ, 1), 256, 0, stream>>>(S, 0);
      pv_kernel<<<dim3(64, 1, 1), 512, 0, stream>>>(
          (const __bf16*)S, Vtb + b * TC, AO + b * TC, 0, 0, 0);
    }
    oproj128_kernel<<<512, 512, 0, stream>>>(AO, Wot, bo, (float*)d_out);
  }
}

// Round 14
// 170.319 us; speedup vs baseline: 1.0404x; 1.0404x over previous
//
#include <hip/hip_runtime.h>
#include <hip/hip_bf16.h>
#include <stdint.h>

// ---------------------------------------------------------------------------
// MultiHeadAttention (no head split): out = softmax_causal((xWq)(xWk)^T/32)(xWv) Wo
// B=4, T=2048, C=1024, fp32 in/out, bf16 MFMA compute.
// Round 14: QKV = 128x256/BK32 TRIPLE-buffer, ONE barrier per K-step
//   {stage t+2; vmcnt(3); read frags t; MFMA t; BAR} — no read/MFMA barrier,
//   waves free-run within the step (fixes r12's phase-lock). 2 WGs/CU.
// QK: 256^2 8-phase causal live-tiles (r11). PV: paired-triangular (r11).
// oproj: 128x256 triple-buffer (r11). Zero-conflict swizzle throughout.
// ---------------------------------------------------------------------------

typedef __attribute__((ext_vector_type(8))) __bf16 bf16x8;
typedef __attribute__((ext_vector_type(4))) __bf16 bf16x4;
typedef __attribute__((ext_vector_type(4))) float f32x4;

#define MFMA16(A, B, C) __builtin_amdgcn_mfma_f32_16x16x32_bf16(A, B, C, 0, 0, 0)
#define BAR() asm volatile("s_barrier" ::: "memory")

#define T_SEQ 2048
#define D_MOD 1024

static __device__ __forceinline__ void gload_lds16(const void* g, void* l) {
  __builtin_amdgcn_global_load_lds(
      (const __attribute__((address_space(1))) void*)g,
      (__attribute__((address_space(3))) void*)l, 16, 0, 0);
}

// ------------------------- elementwise fp32 -> bf16 ------------------------
__global__ void cvt_bf16_kernel(const float* __restrict__ in,
                                __bf16* __restrict__ out, int n8) {
  int i = blockIdx.x * blockDim.x + threadIdx.x;
  if (i < n8) {
    const float4* p = (const float4*)(in + (size_t)i * 8);
    float4 a = p[0], b = p[1];
    bf16x8 o;
    o[0] = (__bf16)a.x; o[1] = (__bf16)a.y; o[2] = (__bf16)a.z; o[3] = (__bf16)a.w;
    o[4] = (__bf16)b.x; o[5] = (__bf16)b.y; o[6] = (__bf16)b.z; o[7] = (__bf16)b.w;
    *(bf16x8*)(out + (size_t)i * 8) = o;
  }
}

// ---------- all four W (K x N fp32) -> Wt (N x K bf16), one launch ---------
__global__ void transpose_cvt4_kernel(const float* __restrict__ Wq,
                                      const float* __restrict__ Wk,
                                      const float* __restrict__ Wv,
                                      const float* __restrict__ Wo,
                                      __bf16* __restrict__ Wqkvt,
                                      __bf16* __restrict__ Wot) {
  __shared__ float tile[32][33];
  const int z = blockIdx.z;
  const float* W = (z == 0) ? Wq : (z == 1) ? Wk : (z == 2) ? Wv : Wo;
  __bf16* Wt = (z < 3) ? (Wqkvt + (size_t)z * 1024 * 1024) : Wot;
  int tx = threadIdx.x, ty = threadIdx.y;
  int bx = blockIdx.x * 32, by = blockIdx.y * 32;
#pragma unroll
  for (int i = 0; i < 4; i++)
    tile[ty + 8 * i][tx] = W[(size_t)(by + ty + 8 * i) * D_MOD + bx + tx];
  __syncthreads();
#pragma unroll
  for (int i = 0; i < 4; i++)
    Wt[(size_t)(bx + ty + 8 * i) * D_MOD + by + tx] = (__bf16)tile[tx][ty + 8 * i];
}

// ==== QKV: 128x256 / BK=32 TRIPLE-buffer, 1 barrier/K-step, 768 WGs ========
// 8 waves (2M x 4N), wave tile 64x64, acc[4][4]. LDS 72KB (3 x 24KB tiles:
// A 8KB + B 16KB). Per K-step t: {stage t+2 -> buf[(t+2)%3]; vmcnt(3)
// [tile t landed at step t-1; drains t+1]; read frags t; MFMA t (compiler
// lgkm wait); BAR}. No mid-barrier: waves/WGs de-phase freely, LDS reads
// overlap other waves' MFMA. Restage tenant t-1 was consumed before
// BAR(t-1) (MFMA's lgkm) -> DMA-vs-read hazard closed by the one barrier.
__global__ __launch_bounds__(512, 2) void qkv256s_kernel(
    const __bf16* __restrict__ A, const __bf16* __restrict__ Bt,
    const float* __restrict__ bq, const float* __restrict__ bk,
    const float* __restrict__ bv, __bf16* __restrict__ Qo,
    __bf16* __restrict__ Ko, __bf16* __restrict__ Vto) {
  constexpr int NT = 32;  // K = 1024, BK = 32
  __shared__ __align__(16) char lds[73728];  // 3 x (A 8KB + B 16KB)
#define TBUF(p) (lds + (p) * 24576)

  const int tid = threadIdx.x;
  const int w = tid >> 6, l = tid & 63;
  const int wr = w >> 2, wc = w & 3;  // 2M x 4N
  const int cpx = gridDim.x >> 3;     // 768 % 8 == 0, bijective XCD swizzle
  const int swz = ((int)blockIdx.x & 7) * cpx + ((int)blockIdx.x >> 3);
  const int bm = (swz / 12) * 128;    // 64 m-tiles
  const int bn = (swz % 12) * 256;    // 12 n-tiles

  const int cswz = (l & 3) ^ ((l >> 3) & 3);           // staging src chunk
  const int rlo = l & 15;                              // frag row within 16
  const int xsw = (((l >> 4) ^ ((l >> 1) & 3)) << 4);  // frag read chunk
  const int srow = w * 16 + (l >> 2);                  // staged row (0..127)

#define STAGE(t, p)                                                    \
  {                                                                    \
    const __bf16* ga = A + (size_t)(bm + srow) * 1024 + (t) * 32 +     \
                       cswz * 8;                                       \
    gload_lds16(ga, TBUF(p) + w * 1024 + l * 16);                      \
    const __bf16* gb = Bt + (size_t)(bn + srow) * 1024 + (t) * 32 +    \
                       cswz * 8;                                       \
    char* d = TBUF(p) + 8192 + w * 1024 + l * 16;                      \
    gload_lds16(gb, d);                                                \
    gload_lds16(gb + (size_t)128 * 1024, d + 8192);                    \
  }

  f32x4 acc[4][4] = {};
  // prologue: tiles 0 and 1 into buffers 0 and 1; land tile 0
  STAGE(0, 0);
  STAGE(1, 1);
  asm volatile("s_waitcnt vmcnt(3)" ::: "memory");  // tile 0 landed
  BAR();

  int pr = 0;  // buffer of tile t
  for (int t = 0; t < NT; ++t) {
    const int ps = (pr + 2 >= 3) ? pr - 1 : pr + 2;  // (t+2)%3
    if (t + 2 < NT) STAGE(t + 2, ps);
    if (t + 1 < NT) asm volatile("s_waitcnt vmcnt(3)" ::: "memory");
    else asm volatile("s_waitcnt vmcnt(0)" ::: "memory");
    // read frags of tile t; MFMA consumes them (compiler inserts lgkmcnt)
    bf16x8 af[4], bf[4];
    {
      char* tb = TBUF(pr);
#pragma unroll
      for (int i = 0; i < 4; i++)
        af[i] = *(const bf16x8*)(tb + (wr * 64 + i * 16 + rlo) * 64 + xsw);
#pragma unroll
      for (int n = 0; n < 4; n++)
        bf[n] = *(const bf16x8*)(tb + 8192 +
                                 (wc * 64 + n * 16 + rlo) * 64 + xsw);
    }
    __builtin_amdgcn_s_setprio(1);
#pragma unroll
    for (int i = 0; i < 4; i++)
#pragma unroll
      for (int n = 0; n < 4; n++)
        acc[i][n] = MFMA16(af[i], bf[n], acc[i][n]);
    __builtin_amdgcn_s_setprio(0);
    BAR();
    pr = (pr + 1 == 3) ? 0 : pr + 1;
  }

  // ---- epilogue: tile lies wholly in one 1024-col segment ----
  const int l4 = (l >> 4) * 4;
  const int seg = bn >> 10;
  const int bnl = bn & 1023;
  if (seg < 2) {
    const float* bs = seg ? bk : bq;
    __bf16* os = seg ? Ko : Qo;
#pragma unroll
    for (int n4 = 0; n4 < 4; n4++) {
      int col = bnl + wc * 64 + n4 * 16 + rlo;
      float bvv = bs[col];
#pragma unroll
      for (int m = 0; m < 4; m++) {
        int rowb = bm + wr * 64 + m * 16 + l4;
#pragma unroll
        for (int r = 0; r < 4; r++)
          os[(size_t)(rowb + r) * D_MOD + col] = (__bf16)(acc[m][n4][r] + bvv);
      }
    }
  } else {
#pragma unroll
    for (int n4 = 0; n4 < 4; n4++) {
      int lcol = bnl + wc * 64 + n4 * 16 + rlo;
      float bvv = bv[lcol];
#pragma unroll
      for (int m = 0; m < 4; m++) {
        int rowb = bm + wr * 64 + m * 16 + l4;  // mult of 4
        int zz = rowb >> 11, tt = rowb & 2047;
        bf16x4 pk;
#pragma unroll
        for (int r = 0; r < 4; r++) pk[r] = (__bf16)(acc[m][n4][r] + bvv);
        *(bf16x4*)(Vto + (size_t)zz * (D_MOD * T_SEQ) + (size_t)lcol * T_SEQ +
                   tt) = pk;
      }
    }
  }
#undef TBUF
#undef STAGE
}

// ================= 256^2 8-phase GEMM (QK: causal, f32 out) ================
// Live tiles only: grid (36, 1, 4), triangular decode (i >= j).
template <int MG, int NG>
static __device__ __forceinline__ void mfma_quad(f32x4 (&acc)[8][4],
                                                 const bf16x8 (&aR)[4][2],
                                                 const bf16x8 (&bR)[2][2]) {
#pragma unroll
  for (int i = 0; i < 4; i++)
#pragma unroll
    for (int n = 0; n < 2; n++)
#pragma unroll
      for (int kk = 0; kk < 2; kk++)
        acc[MG * 4 + i][NG * 2 + n] =
            MFMA16(aR[i][kk], bR[n][kk], acc[MG * 4 + i][NG * 2 + n]);
}

__global__ __launch_bounds__(512, 2) void qk_kernel(
    const __bf16* __restrict__ A, const __bf16* __restrict__ Bt,
    float* __restrict__ So, size_t bsA, size_t bsB, size_t bsC) {
  constexpr int NT = 16;
  __shared__ __align__(16) char lds[131072];
#define ABUF(p, h) (lds + ((p) * 2 + (h)) * 16384)
#define BBUF(p, h) (lds + 65536 + ((p) * 2 + (h)) * 16384)

  const int tid = threadIdx.x;
  const int w = tid >> 6, l = tid & 63;
  const int wr = w >> 2, wc = w & 3;
  int x = (int)blockIdx.x;
  int ti = 0;
  while (x >= ti + 1) { x -= ti + 1; ++ti; }
  const int tj = x;
  const int bm = ti * 256, bn = tj * 256;
  const int z = blockIdx.z;
  A += (size_t)z * bsA;
  Bt += (size_t)z * bsB;

  const int grow = l >> 2;
  const int cswz = (l & 3) ^ ((l >> 3) & 3);
  const int rlo = l & 15;
  const int xsw = (((l >> 4) ^ ((l >> 1) & 3)) << 4);

#define STAGE_A(t, h)                                                       \
  {                                                                         \
    const __bf16* g = A + (size_t)(bm + (h) * 128 + w * 16 + grow) * 1024 + \
                      (t) * 64 + cswz * 8;                                  \
    char* d = ABUF((t) & 1, h) + w * 1024 + l * 16;                         \
    gload_lds16(g, d);                                                      \
    gload_lds16(g + 32, d + 8192);                                          \
  }
#define STAGE_B(t, h)                                                       \
  {                                                                         \
    const __bf16* g = Bt + (size_t)(bn + (h) * 128 + w * 16 + grow) * 1024 +\
                      (t) * 64 + cswz * 8;                                  \
    char* d = BBUF((t) & 1, h) + w * 1024 + l * 16;                         \
    gload_lds16(g, d);                                                      \
    gload_lds16(g + 32, d + 8192);                                          \
  }
#define LDA_FRAG(p, g, i, kk)                                     \
  (*(const bf16x8*)(ABUF(p, wr) + (kk) * 8192 +                   \
                    ((g) * 64 + (i) * 16 + rlo) * 64 + xsw))
#define LDB_FRAG(p, g, n, kk)                                     \
  (*(const bf16x8*)(BBUF(p, (wc >> 1)) + (kk) * 8192 +            \
                    ((wc & 1) * 64 + (g) * 32 + (n) * 16 + rlo) * 64 + xsw))

  f32x4 acc[8][4] = {};
  STAGE_A(0, 0); STAGE_A(0, 1);
  STAGE_B(0, 0); STAGE_B(0, 1);
  STAGE_A(1, 0); STAGE_A(1, 1);
  asm volatile("s_waitcnt vmcnt(4)" ::: "memory");
  BAR();

  for (int t = 0; t < NT; ++t) {
    const int p = t & 1;
    bf16x8 a[4][2], b[2][2];
#pragma unroll
    for (int i = 0; i < 4; i++) {
      a[i][0] = LDA_FRAG(p, 0, i, 0);
      a[i][1] = LDA_FRAG(p, 0, i, 1);
    }
#pragma unroll
    for (int n = 0; n < 2; n++) {
      b[n][0] = LDB_FRAG(p, 0, n, 0);
      b[n][1] = LDB_FRAG(p, 0, n, 1);
    }
    if (t + 1 < NT) STAGE_B(t + 1, 0);
    BAR();
    __builtin_amdgcn_s_setprio(1);
    mfma_quad<0, 0>(acc, a, b);
    __builtin_amdgcn_s_setprio(0);
    BAR();
    bf16x8 b2[2][2];
#pragma unroll
    for (int n = 0; n < 2; n++) {
      b2[n][0] = LDB_FRAG(p, 1, n, 0);
      b2[n][1] = LDB_FRAG(p, 1, n, 1);
    }
    if (t + 1 < NT) STAGE_B(t + 1, 1);
    BAR();
    __builtin_amdgcn_s_setprio(1);
    mfma_quad<0, 1>(acc, a, b2);
    __builtin_amdgcn_s_setprio(0);
    BAR();
#pragma unroll
    for (int i = 0; i < 4; i++) {
      a[i][0] = LDA_FRAG(p, 1, i, 0);
      a[i][1] = LDA_FRAG(p, 1, i, 1);
    }
    BAR();
    __builtin_amdgcn_s_setprio(1);
    mfma_quad<1, 1>(acc, a, b2);
    __builtin_amdgcn_s_setprio(0);
    BAR();
#pragma unroll
    for (int n = 0; n < 2; n++) {
      b[n][0] = LDB_FRAG(p, 0, n, 0);
      b[n][1] = LDB_FRAG(p, 0, n, 1);
    }
    if (t + 2 < NT) {
      STAGE_A(t + 2, 0); STAGE_A(t + 2, 1);
      BAR();
      __builtin_amdgcn_s_setprio(1);
      mfma_quad<1, 0>(acc, a, b);
      __builtin_amdgcn_s_setprio(0);
      asm volatile("s_waitcnt vmcnt(4)" ::: "memory");
      BAR();
    } else {
      BAR();
      __builtin_amdgcn_s_setprio(1);
      mfma_quad<1, 0>(acc, a, b);
      __builtin_amdgcn_s_setprio(0);
      asm volatile("s_waitcnt vmcnt(0)" ::: "memory");
      BAR();
    }
  }

  float* os = So + (size_t)z * bsC;
#pragma unroll
  for (int n4 = 0; n4 < 4; n4++) {
    int col = bn + wc * 64 + n4 * 16 + rlo;
#pragma unroll
    for (int mi = 0; mi < 8; mi++) {
      int rowb = bm + wr * 128 + mi * 16 + (l >> 4) * 4;
#pragma unroll
      for (int r = 0; r < 4; r++) {
        int row = rowb + r;
        float v = acc[mi][n4][r] * 0.03125f;  // 1/sqrt(1024)
        if (col > row) v = -1e30f;
        os[(size_t)row * T_SEQ + col] = v;
      }
    }
  }
#undef ABUF
#undef BBUF
#undef STAGE_A
#undef STAGE_B
#undef LDA_FRAG
#undef LDB_FRAG
}

// ======== PV: 128x128 paired-triangular GEMM (34 BK-steps/WG, 1 round) =====
__global__ __launch_bounds__(512, 2) void pv_kernel(
    const __bf16* __restrict__ Ap, const __bf16* __restrict__ Btp,
    __bf16* __restrict__ Op, size_t bsA, size_t bsB, size_t bsC) {
  __shared__ __align__(16) char lds[98304];
#define ABUF(p3) (lds + (p3) * 16384)
#define BBUF(p3) (lds + 49152 + (p3) * 16384)

  const int tid = threadIdx.x;
  const int w = tid >> 6, l = tid & 63;
  const int wr = w >> 2, wc = w & 3;  // 2M x 4N; wave tile 64x32
  const int pid = (int)blockIdx.x >> 3;
  const int bn = ((int)blockIdx.x & 7) * 128;
  const int z = blockIdx.z;
  const __bf16* A = Ap + (size_t)z * bsA;
  const __bf16* Bt = Btp + (size_t)z * bsB;
  __bf16* O = Op + (size_t)z * bsC;

  const int grow = w * 16 + (l >> 2);
  const int cswz = (l & 3) ^ ((l >> 3) & 3);
  const int rlo = l & 15;
  const int xsw = (((l >> 4) ^ ((l >> 1) & 3)) << 4);

#define PSTAGE_A(t, p3)                                                      \
  {                                                                          \
    const __bf16* g = A + (size_t)(bm + grow) * 4096 + (t) * 64 + cswz * 8;  \
    char* d = ABUF(p3) + w * 1024 + l * 16;                                  \
    gload_lds16(g, d);                                                       \
    gload_lds16(g + 32, d + 8192);                                           \
  }
#define PSTAGE_B(t, p3)                                                      \
  {                                                                          \
    const __bf16* g = Bt + (size_t)(bn + grow) * 2048 + (t) * 64 + cswz * 8; \
    char* d = BBUF(p3) + w * 1024 + l * 16;                                  \
    gload_lds16(g, d);                                                       \
    gload_lds16(g + 32, d + 8192);                                           \
  }
#define PLDA(p3, i, kk)                                           \
  (*(const bf16x8*)(ABUF(p3) + (kk) * 8192 +                      \
                    (wr * 64 + (i) * 16 + rlo) * 64 + xsw))
#define PLDB(p3, n, kk)                                           \
  (*(const bf16x8*)(BBUF(p3) + (kk) * 8192 +                      \
                    (wc * 32 + (n) * 16 + rlo) * 64 + xsw))

#pragma unroll
  for (int seg = 0; seg < 2; ++seg) {
    const int i = seg ? (15 - pid) : pid;
    const int bm = i * 128;
    const int NT = (i + 1) * 2;  // BK=64 steps over K=(i+1)*128
    f32x4 acc[4][2] = {};

    PSTAGE_A(0, 0); PSTAGE_B(0, 0);
    if (NT > 1) { PSTAGE_A(1, 1); PSTAGE_B(1, 1); }
    asm volatile("s_waitcnt vmcnt(4)" ::: "memory");
    BAR();

    int p = 0, pn2 = 2;
    for (int t = 0; t < NT; ++t) {
      bf16x8 af[4][2], bfv[2][2];
#pragma unroll
      for (int m = 0; m < 4; m++) {
        af[m][0] = PLDA(p, m, 0);
        af[m][1] = PLDA(p, m, 1);
      }
#pragma unroll
      for (int n = 0; n < 2; n++) {
        bfv[n][0] = PLDB(p, n, 0);
        bfv[n][1] = PLDB(p, n, 1);
      }
      if (t + 2 < NT) { PSTAGE_A(t + 2, pn2); PSTAGE_B(t + 2, pn2); }
      BAR();
      __builtin_amdgcn_s_setprio(1);
#pragma unroll
      for (int m = 0; m < 4; m++)
#pragma unroll
        for (int n = 0; n < 2; n++) {
          acc[m][n] = MFMA16(af[m][0], bfv[n][0], acc[m][n]);
          acc[m][n] = MFMA16(af[m][1], bfv[n][1], acc[m][n]);
        }
      __builtin_amdgcn_s_setprio(0);
      if (t + 2 < NT) asm volatile("s_waitcnt vmcnt(4)" ::: "memory");
      else asm volatile("s_waitcnt vmcnt(0)" ::: "memory");
      BAR();
      p = (p + 1 == 3) ? 0 : p + 1;
      pn2 = (pn2 + 1 == 3) ? 0 : pn2 + 1;
    }

#pragma unroll
    for (int n = 0; n < 2; n++) {
      int col = bn + wc * 32 + n * 16 + rlo;
#pragma unroll
      for (int m = 0; m < 4; m++) {
        int rowb = bm + wr * 64 + m * 16 + (l >> 4) * 4;
#pragma unroll
        for (int r = 0; r < 4; r++)
          O[(size_t)(rowb + r) * D_MOD + col] = (__bf16)acc[m][n][r];
      }
    }
    BAR();  // LDS safe before next segment restage
  }
#undef ABUF
#undef BBUF
#undef PSTAGE_A
#undef PSTAGE_B
#undef PLDA
#undef PLDB
}

// ============ 128x256 triple-buffer GEMM (out-proj, f32 out + bias) ========
__global__ __launch_bounds__(512, 2) void oproj_kernel(
    const __bf16* __restrict__ A, const __bf16* __restrict__ Bt,
    const float* __restrict__ b0, float* __restrict__ o0) {
  constexpr int NT = 16;
  __shared__ __align__(16) char lds[147456];
#define ABUF(p3) (lds + (p3) * 16384)
#define BBUF(p3) (lds + 49152 + (p3) * 32768)

  const int tid = threadIdx.x;
  const int w = tid >> 6, l = tid & 63;
  const int wr = w >> 2, wc = w & 3;
  const int cpx = gridDim.x >> 3;
  const int swz = ((int)blockIdx.x & 7) * cpx + ((int)blockIdx.x >> 3);
  const int bm = (swz >> 2) * 128, bn = (swz & 3) * 256;

  const int grow = w * 16 + (l >> 2);
  const int cswz = (l & 3) ^ ((l >> 3) & 3);
  const int rlo = l & 15;
  const int xsw = (((l >> 4) ^ ((l >> 1) & 3)) << 4);

#define STAGE_A(t, p3)                                                       \
  {                                                                          \
    const __bf16* g = A + (size_t)(bm + grow) * 1024 + (t) * 64 + cswz * 8;  \
    char* d = ABUF(p3) + w * 1024 + l * 16;                                  \
    gload_lds16(g, d);                                                       \
    gload_lds16(g + 32, d + 8192);                                           \
  }
#define STAGE_B(t, p3)                                                       \
  {                                                                          \
    const __bf16* g = Bt + (size_t)(bn + grow) * 1024 + (t) * 64 + cswz * 8; \
    char* d = BBUF(p3) + w * 1024 + l * 16;                                  \
    gload_lds16(g, d);                                                       \
    gload_lds16(g + 32, d + 16384);                                          \
    const __bf16* g2 = g + (size_t)128 * 1024;                               \
    gload_lds16(g2, d + 8192);                                               \
    gload_lds16(g2 + 32, d + 8192 + 16384);                                  \
  }
#define LDA_FRAG(p3, i, kk)                                       \
  (*(const bf16x8*)(ABUF(p3) + (kk) * 8192 +                      \
                    (wr * 64 + (i) * 16 + rlo) * 64 + xsw))
#define LDB_FRAG(p3, n, kk)                                       \
  (*(const bf16x8*)(BBUF(p3) + (kk) * 16384 +                     \
                    (wc * 64 + (n) * 16 + rlo) * 64 + xsw))

  f32x4 acc[4][4] = {};
  STAGE_A(0, 0); STAGE_B(0, 0);
  STAGE_A(1, 1); STAGE_B(1, 1);
  asm volatile("s_waitcnt vmcnt(6)" ::: "memory");
  BAR();

  int p = 0, pn2 = 2;
  for (int t = 0; t < NT; ++t) {
    bf16x8 af[4][2], bf01[2][2], bf23[2][2];
#pragma unroll
    for (int i = 0; i < 4; i++) {
      af[i][0] = LDA_FRAG(p, i, 0);
      af[i][1] = LDA_FRAG(p, i, 1);
    }
#pragma unroll
    for (int n = 0; n < 2; n++) {
      bf01[n][0] = LDB_FRAG(p, n, 0);
      bf01[n][1] = LDB_FRAG(p, n, 1);
    }
    if (t + 2 < NT) STAGE_A(t + 2, pn2);
    BAR();
    __builtin_amdgcn_s_setprio(1);
#pragma unroll
    for (int i = 0; i < 4; i++)
#pragma unroll
      for (int n = 0; n < 2; n++) {
        acc[i][n] = MFMA16(af[i][0], bf01[n][0], acc[i][n]);
        acc[i][n] = MFMA16(af[i][1], bf01[n][1], acc[i][n]);
      }
    __builtin_amdgcn_s_setprio(0);
    BAR();
#pragma unroll
    for (int n = 0; n < 2; n++) {
      bf23[n][0] = LDB_FRAG(p, n + 2, 0);
      bf23[n][1] = LDB_FRAG(p, n + 2, 1);
    }
    if (t + 2 < NT) STAGE_B(t + 2, pn2);
    BAR();
    __builtin_amdgcn_s_setprio(1);
#pragma unroll
    for (int i = 0; i < 4; i++)
#pragma unroll
      for (int n = 0; n < 2; n++) {
        acc[i][n + 2] = MFMA16(af[i][0], bf23[n][0], acc[i][n + 2]);
        acc[i][n + 2] = MFMA16(af[i][1], bf23[n][1], acc[i][n + 2]);
      }
    __builtin_amdgcn_s_setprio(0);
    if (t + 2 < NT) {
      asm volatile("s_waitcnt vmcnt(6)" ::: "memory");
    } else {
      asm volatile("s_waitcnt vmcnt(0)" ::: "memory");
    }
    BAR();
    p = (p + 1 == 3) ? 0 : p + 1;
    pn2 = (pn2 + 1 == 3) ? 0 : pn2 + 1;
  }

#pragma unroll
  for (int n = 0; n < 4; n++) {
    int col = bn + wc * 64 + n * 16 + rlo;
    float bvv = b0[col];
#pragma unroll
    for (int m = 0; m < 4; m++) {
      int rowb = bm + wr * 64 + m * 16 + (l >> 4) * 4;
#pragma unroll
      for (int r = 0; r < 4; r++)
        o0[(size_t)(rowb + r) * D_MOD + col] = acc[m][n][r] + bvv;
    }
  }
#undef ABUF
#undef BBUF
#undef STAGE_A
#undef STAGE_B
#undef LDA_FRAG
#undef LDB_FRAG
}

// ----------------------- row softmax, P bf16 in-place ----------------------
__global__ __launch_bounds__(256) void softmax_kernel(float* __restrict__ S,
                                                      size_t bstride) {
  const int t = blockIdx.x, b = blockIdx.y;
  float* Srow = S + (size_t)b * bstride + (size_t)t * T_SEQ;
  __bf16* Prow = (__bf16*)Srow;
  const int L = ((t + 1) + 127) & ~127;
  const int tid = threadIdx.x;
  const int base = tid * 8;
  const bool act = base < L;
  float v[8];
  float m = -1e30f;
  if (act) {
    float4 a = *(const float4*)(Srow + base);
    float4 c = *(const float4*)(Srow + base + 4);
    v[0] = a.x; v[1] = a.y; v[2] = a.z; v[3] = a.w;
    v[4] = c.x; v[5] = c.y; v[6] = c.z; v[7] = c.w;
#pragma unroll
    for (int j = 0; j < 8; j++) m = fmaxf(m, v[j]);
  }
#pragma unroll
  for (int off = 1; off < 64; off <<= 1) m = fmaxf(m, __shfl_xor(m, off));
  __shared__ float redm[4], reds[4];
  const int wave = tid >> 6, lane = tid & 63;
  if (lane == 0) redm[wave] = m;
  __syncthreads();
  m = fmaxf(fmaxf(redm[0], redm[1]), fmaxf(redm[2], redm[3]));
  float p[8];
  float s = 0.f;
  if (act) {
#pragma unroll
    for (int j = 0; j < 8; j++) {
      p[j] = __expf(v[j] - m);
      s += p[j];
    }
  }
#pragma unroll
  for (int off = 1; off < 64; off <<= 1) s += __shfl_xor(s, off);
  if (lane == 0) reds[wave] = s;
  __syncthreads();  // fences: reads done before in-place bf16 writes
  const float inv = 1.0f / (reds[0] + reds[1] + reds[2] + reds[3]);
  if (act) {
    bf16x8 o;
#pragma unroll
    for (int j = 0; j < 8; j++) o[j] = (__bf16)(p[j] * inv);
    *(bf16x8*)(Prow + base) = o;
  }
}

// ---------------------------------------------------------------------------
extern "C" void kernel_launch(void* const* d_in, const int* in_sizes, int n_in,
                              void* d_out, int out_size, void* d_ws,
                              size_t ws_size, hipStream_t stream) {
  const float* x = (const float*)d_in[0];
  const float* Wq = (const float*)d_in[1];
  const float* bq = (const float*)d_in[2];
  const float* Wk = (const float*)d_in[3];
  const float* bk = (const float*)d_in[4];
  const float* Wv = (const float*)d_in[5];
  const float* bv = (const float*)d_in[6];
  const float* Wo = (const float*)d_in[7];
  const float* bo = (const float*)d_in[8];

  char* ws = (char*)d_ws;
  const size_t MB = 1u << 20;
  const size_t TC = (size_t)T_SEQ * D_MOD;  // 2M elems / batch
  const size_t TT = (size_t)T_SEQ * T_SEQ;  // 4M elems / batch
  __bf16* xb    = (__bf16*)(ws);            // [0,16) MB ; dead after QKV
  __bf16* Wqkvt = (__bf16*)(ws + 16 * MB);  // [16,22)  3072x1024
  __bf16* Wot   = (__bf16*)(ws + 22 * MB);  // [22,24)
  __bf16* Qb    = (__bf16*)(ws + 24 * MB);  // [24,40) ; later AO
  __bf16* Kb    = (__bf16*)(ws + 40 * MB);  // [40,56)
  __bf16* Vtb   = (__bf16*)(ws + 56 * MB);  // [56,72)  V^T direct from QKV

  // 1) x -> bf16
  cvt_bf16_kernel<<<4096, 256, 0, stream>>>(x, xb, 8192 * D_MOD / 8);
  // 2) weight transposes (one dispatch)
  transpose_cvt4_kernel<<<dim3(32, 32, 4), dim3(32, 8), 0, stream>>>(
      Wq, Wk, Wv, Wo, Wqkvt, Wot);
  // 3) fused QKV projection (1-barrier triple-buffer); V written transposed
  qkv256s_kernel<<<768, 512, 0, stream>>>(xb, Wqkvt, bq, bk, bv, Qb, Kb, Vtb);

  const bool batched = ws_size >= 137 * MB;
  if (batched) {
    float* S = (float*)(ws + 72 * MB);  // [72,136) fp32, 4 batches
    __bf16* AO = Qb;                    // Q dead after QK
    // 4) S = QK^T * scale, causal: live 256^2 tiles only (36 per batch)
    qk_kernel<<<dim3(36, 1, 4), 512, 0, stream>>>(Qb, Kb, S, TC, TC, TT);
    // 5) row softmax, P bf16 in-place (row stride 4096 bf16)
    softmax_kernel<<<dim3(T_SEQ, 4), 256, 0, stream>>>(S, TT);
    // 6) O = P V, paired triangular 128x128 tiles (1 balanced round)
    pv_kernel<<<dim3(64, 1, 4), 512, 0, stream>>>((const __bf16*)S, Vtb, AO,
                                                  TT * 2, TC, TC);
    // 7) out projection (f32 out)
    oproj_kernel<<<256, 512, 0, stream>>>(AO, Wot, bo, (float*)d_out);
  } else {
    // per-batch fallback: S reuses xb region (dead after QKV), AO over Qb
    float* S = (float*)(ws);
    __bf16* AO = Qb;
    for (int b = 0; b < 4; ++b) {
      qk_kernel<<<dim3(36, 1, 1), 512, 0, stream>>>(Qb + b * TC, Kb + b * TC,
                                                    S, 0, 0, 0);
      softmax_kernel<<<dim3(T_SEQ, 1), 256, 0, stream>>>(S, 0);
      pv_kernel<<<dim3(64, 1, 1), 512, 0, stream>>>(
          (const __bf16*)S, Vtb + b * TC, AO + b * TC, 0, 0, 0);
    }
    oproj_kernel<<<256, 512, 0, stream>>>(AO, Wot, bo, (float*)d_out);
  }
}

// Round 15
// 168.797 us; speedup vs baseline: 1.0498x; 1.0090x over previous
//
#include <hip/hip_runtime.h>
#include <hip/hip_bf16.h>
#include <stdint.h>

// ---------------------------------------------------------------------------
// MultiHeadAttention (no head split): out = softmax_causal((xWq)(xWk)^T/32)(xWv) Wo
// B=4, T=2048, C=1024, fp32 in/out, bf16 MFMA compute.
// Round 15 = stable-best consolidation:
//   QKV: r12 qkv256 (128x256/BK32 dbuf, 48KiB, 2 WGs/CU) — absmax-stable
//        (r14's 1-barrier variant showed output nondeterminism -> reverted).
//   QK: 256^2 8-phase causal live-tiles. PV: paired-triangular.
//   oproj: 128x256 triple-buffer. prep: cvt + 4 transposes in ONE dispatch.
// Zero-conflict LDS swizzle (phys chunk = logical ^ ((row>>1)&3)) throughout.
// ---------------------------------------------------------------------------

typedef __attribute__((ext_vector_type(8))) __bf16 bf16x8;
typedef __attribute__((ext_vector_type(4))) __bf16 bf16x4;
typedef __attribute__((ext_vector_type(4))) float f32x4;

#define MFMA16(A, B, C) __builtin_amdgcn_mfma_f32_16x16x32_bf16(A, B, C, 0, 0, 0)
#define BAR() asm volatile("s_barrier" ::: "memory")

#define T_SEQ 2048
#define D_MOD 1024

static __device__ __forceinline__ void gload_lds16(const void* g, void* l) {
  __builtin_amdgcn_global_load_lds(
      (const __attribute__((address_space(1))) void*)g,
      (__attribute__((address_space(3))) void*)l, 16, 0, 0);
}

// ========== prep: x -> bf16 (blocks < 4096) + W transposes (>= 4096) =======
__global__ void prep_kernel(const float* __restrict__ x,
                            const float* __restrict__ Wq,
                            const float* __restrict__ Wk,
                            const float* __restrict__ Wv,
                            const float* __restrict__ Wo,
                            __bf16* __restrict__ xb,
                            __bf16* __restrict__ Wqkvt,
                            __bf16* __restrict__ Wot) {
  const int b = blockIdx.x;
  if (b < 4096) {
    // convert 8M fp32 -> bf16, 2048 elems per block
    int i = b * 256 + threadIdx.x;
    const float4* p = (const float4*)(x + (size_t)i * 8);
    float4 a = p[0], c = p[1];
    bf16x8 o;
    o[0] = (__bf16)a.x; o[1] = (__bf16)a.y; o[2] = (__bf16)a.z; o[3] = (__bf16)a.w;
    o[4] = (__bf16)c.x; o[5] = (__bf16)c.y; o[6] = (__bf16)c.z; o[7] = (__bf16)c.w;
    *(bf16x8*)(xb + (size_t)i * 8) = o;
  } else {
    __shared__ float tile[32][33];
    const int m = b - 4096;          // 0..4095
    const int z = m >> 10;           // which W
    const int t = m & 1023;
    const int bx = (t & 31) * 32, by = (t >> 5) * 32;
    const float* W = (z == 0) ? Wq : (z == 1) ? Wk : (z == 2) ? Wv : Wo;
    __bf16* Wt = (z < 3) ? (Wqkvt + (size_t)z * 1024 * 1024) : Wot;
    const int tx = threadIdx.x & 31, ty = threadIdx.x >> 5;
#pragma unroll
    for (int i = 0; i < 4; i++)
      tile[ty + 8 * i][tx] = W[(size_t)(by + ty + 8 * i) * D_MOD + bx + tx];
    __syncthreads();
#pragma unroll
    for (int i = 0; i < 4; i++)
      Wt[(size_t)(bx + ty + 8 * i) * D_MOD + by + tx] =
          (__bf16)tile[tx][ty + 8 * i];
  }
}

// ======= QKV: 128x256 / BK=32 dbuf GEMM, 48KiB LDS, 2 WGs/CU, 768 WGs ======
// (r12, proven stable). Per tile: {8 ds_read; lgkmcnt(0); BAR}
//                                 {stage t+2 in-place; 16 MFMA; vmcnt(3); BAR}
__global__ __launch_bounds__(512, 2) void qkv256_kernel(
    const __bf16* __restrict__ A, const __bf16* __restrict__ Bt,
    const float* __restrict__ bq, const float* __restrict__ bk,
    const float* __restrict__ bv, __bf16* __restrict__ Qo,
    __bf16* __restrict__ Ko, __bf16* __restrict__ Vto) {
  constexpr int NT = 32;  // K = 1024, BK = 32
  __shared__ __align__(16) char lds[49152];
#define ABUF(p) (lds + (p) * 8192)
#define BBUF(p) (lds + 16384 + (p) * 16384)

  const int tid = threadIdx.x;
  const int w = tid >> 6, l = tid & 63;
  const int wr = w >> 2, wc = w & 3;  // 2M x 4N
  const int cpx = gridDim.x >> 3;     // 768 % 8 == 0, bijective XCD swizzle
  const int swz = ((int)blockIdx.x & 7) * cpx + ((int)blockIdx.x >> 3);
  const int bm = (swz / 12) * 128;    // 64 m-tiles
  const int bn = (swz % 12) * 256;    // 12 n-tiles

  const int cswz = (l & 3) ^ ((l >> 3) & 3);           // staging src chunk
  const int rlo = l & 15;                              // frag row within 16
  const int xsw = (((l >> 4) ^ ((l >> 1) & 3)) << 4);  // frag read chunk
  const int srow = w * 16 + (l >> 2);                  // staged row (0..127)

#define STAGE_A(t, p)                                                  \
  {                                                                    \
    const __bf16* g = A + (size_t)(bm + srow) * 1024 + (t) * 32 +      \
                      cswz * 8;                                        \
    gload_lds16(g, ABUF(p) + w * 1024 + l * 16);                       \
  }
#define STAGE_B(t, p)                                                  \
  {                                                                    \
    const __bf16* g0 = Bt + (size_t)(bn + srow) * 1024 + (t) * 32 +    \
                       cswz * 8;                                       \
    char* d = BBUF(p) + w * 1024 + l * 16;                             \
    gload_lds16(g0, d);                                                \
    gload_lds16(g0 + (size_t)128 * 1024, d + 8192);                    \
  }

  f32x4 acc[4][4] = {};
  STAGE_A(0, 0); STAGE_B(0, 0);
  STAGE_A(1, 1); STAGE_B(1, 1);
  asm volatile("s_waitcnt vmcnt(3)" ::: "memory");  // tile 0's 3 landed
  BAR();

  for (int t = 0; t < NT; ++t) {
    const int p = t & 1;
    bf16x8 af[4], bf[4];
#pragma unroll
    for (int i = 0; i < 4; i++)
      af[i] = *(const bf16x8*)(ABUF(p) + (wr * 64 + i * 16 + rlo) * 64 + xsw);
#pragma unroll
    for (int n = 0; n < 4; n++)
      bf[n] = *(const bf16x8*)(BBUF(p) + (wc * 64 + n * 16 + rlo) * 64 + xsw);
    asm volatile("s_waitcnt lgkmcnt(0)" ::: "memory");  // reads retired
    BAR();  // all waves done reading buf p -> in-place restage safe
    if (t + 2 < NT) {
      STAGE_A(t + 2, p);
      STAGE_B(t + 2, p);
    }
    __builtin_amdgcn_s_setprio(1);
#pragma unroll
    for (int i = 0; i < 4; i++)
#pragma unroll
      for (int n = 0; n < 4; n++)
        acc[i][n] = MFMA16(af[i], bf[n], acc[i][n]);
    __builtin_amdgcn_s_setprio(0);
    if (t + 2 < NT) asm volatile("s_waitcnt vmcnt(3)" ::: "memory");
    else asm volatile("s_waitcnt vmcnt(0)" ::: "memory");
    BAR();
  }

  const int l4 = (l >> 4) * 4;
  const int seg = bn >> 10;
  const int bnl = bn & 1023;
  if (seg < 2) {
    const float* bs = seg ? bk : bq;
    __bf16* os = seg ? Ko : Qo;
#pragma unroll
    for (int n4 = 0; n4 < 4; n4++) {
      int col = bnl + wc * 64 + n4 * 16 + rlo;
      float bvv = bs[col];
#pragma unroll
      for (int m = 0; m < 4; m++) {
        int rowb = bm + wr * 64 + m * 16 + l4;
#pragma unroll
        for (int r = 0; r < 4; r++)
          os[(size_t)(rowb + r) * D_MOD + col] = (__bf16)(acc[m][n4][r] + bvv);
      }
    }
  } else {
#pragma unroll
    for (int n4 = 0; n4 < 4; n4++) {
      int lcol = bnl + wc * 64 + n4 * 16 + rlo;
      float bvv = bv[lcol];
#pragma unroll
      for (int m = 0; m < 4; m++) {
        int rowb = bm + wr * 64 + m * 16 + l4;  // mult of 4
        int zz = rowb >> 11, tt = rowb & 2047;
        bf16x4 pk;
#pragma unroll
        for (int r = 0; r < 4; r++) pk[r] = (__bf16)(acc[m][n4][r] + bvv);
        *(bf16x4*)(Vto + (size_t)zz * (D_MOD * T_SEQ) + (size_t)lcol * T_SEQ +
                   tt) = pk;
      }
    }
  }
#undef ABUF
#undef BBUF
#undef STAGE_A
#undef STAGE_B
}

// ================= 256^2 8-phase GEMM (QK: causal, f32 out) ================
// Live tiles only: grid (36, 1, 4), triangular decode (i >= j).
template <int MG, int NG>
static __device__ __forceinline__ void mfma_quad(f32x4 (&acc)[8][4],
                                                 const bf16x8 (&aR)[4][2],
                                                 const bf16x8 (&bR)[2][2]) {
#pragma unroll
  for (int i = 0; i < 4; i++)
#pragma unroll
    for (int n = 0; n < 2; n++)
#pragma unroll
      for (int kk = 0; kk < 2; kk++)
        acc[MG * 4 + i][NG * 2 + n] =
            MFMA16(aR[i][kk], bR[n][kk], acc[MG * 4 + i][NG * 2 + n]);
}

__global__ __launch_bounds__(512, 2) void qk_kernel(
    const __bf16* __restrict__ A, const __bf16* __restrict__ Bt,
    float* __restrict__ So, size_t bsA, size_t bsB, size_t bsC) {
  constexpr int NT = 16;
  __shared__ __align__(16) char lds[131072];
#define ABUF(p, h) (lds + ((p) * 2 + (h)) * 16384)
#define BBUF(p, h) (lds + 65536 + ((p) * 2 + (h)) * 16384)

  const int tid = threadIdx.x;
  const int w = tid >> 6, l = tid & 63;
  const int wr = w >> 2, wc = w & 3;
  int x = (int)blockIdx.x;
  int ti = 0;
  while (x >= ti + 1) { x -= ti + 1; ++ti; }
  const int tj = x;
  const int bm = ti * 256, bn = tj * 256;
  const int z = blockIdx.z;
  A += (size_t)z * bsA;
  Bt += (size_t)z * bsB;

  const int grow = l >> 2;
  const int cswz = (l & 3) ^ ((l >> 3) & 3);
  const int rlo = l & 15;
  const int xsw = (((l >> 4) ^ ((l >> 1) & 3)) << 4);

#define STAGE_A(t, h)                                                       \
  {                                                                         \
    const __bf16* g = A + (size_t)(bm + (h) * 128 + w * 16 + grow) * 1024 + \
                      (t) * 64 + cswz * 8;                                  \
    char* d = ABUF((t) & 1, h) + w * 1024 + l * 16;                         \
    gload_lds16(g, d);                                                      \
    gload_lds16(g + 32, d + 8192);                                          \
  }
#define STAGE_B(t, h)                                                       \
  {                                                                         \
    const __bf16* g = Bt + (size_t)(bn + (h) * 128 + w * 16 + grow) * 1024 +\
                      (t) * 64 + cswz * 8;                                  \
    char* d = BBUF((t) & 1, h) + w * 1024 + l * 16;                         \
    gload_lds16(g, d);                                                      \
    gload_lds16(g + 32, d + 8192);                                          \
  }
#define LDA_FRAG(p, g, i, kk)                                     \
  (*(const bf16x8*)(ABUF(p, wr) + (kk) * 8192 +                   \
                    ((g) * 64 + (i) * 16 + rlo) * 64 + xsw))
#define LDB_FRAG(p, g, n, kk)                                     \
  (*(const bf16x8*)(BBUF(p, (wc >> 1)) + (kk) * 8192 +            \
                    ((wc & 1) * 64 + (g) * 32 + (n) * 16 + rlo) * 64 + xsw))

  f32x4 acc[8][4] = {};
  STAGE_A(0, 0); STAGE_A(0, 1);
  STAGE_B(0, 0); STAGE_B(0, 1);
  STAGE_A(1, 0); STAGE_A(1, 1);
  asm volatile("s_waitcnt vmcnt(4)" ::: "memory");
  BAR();

  for (int t = 0; t < NT; ++t) {
    const int p = t & 1;
    bf16x8 a[4][2], b[2][2];
#pragma unroll
    for (int i = 0; i < 4; i++) {
      a[i][0] = LDA_FRAG(p, 0, i, 0);
      a[i][1] = LDA_FRAG(p, 0, i, 1);
    }
#pragma unroll
    for (int n = 0; n < 2; n++) {
      b[n][0] = LDB_FRAG(p, 0, n, 0);
      b[n][1] = LDB_FRAG(p, 0, n, 1);
    }
    if (t + 1 < NT) STAGE_B(t + 1, 0);
    BAR();
    __builtin_amdgcn_s_setprio(1);
    mfma_quad<0, 0>(acc, a, b);
    __builtin_amdgcn_s_setprio(0);
    BAR();
    bf16x8 b2[2][2];
#pragma unroll
    for (int n = 0; n < 2; n++) {
      b2[n][0] = LDB_FRAG(p, 1, n, 0);
      b2[n][1] = LDB_FRAG(p, 1, n, 1);
    }
    if (t + 1 < NT) STAGE_B(t + 1, 1);
    BAR();
    __builtin_amdgcn_s_setprio(1);
    mfma_quad<0, 1>(acc, a, b2);
    __builtin_amdgcn_s_setprio(0);
    BAR();
#pragma unroll
    for (int i = 0; i < 4; i++) {
      a[i][0] = LDA_FRAG(p, 1, i, 0);
      a[i][1] = LDA_FRAG(p, 1, i, 1);
    }
    BAR();
    __builtin_amdgcn_s_setprio(1);
    mfma_quad<1, 1>(acc, a, b2);
    __builtin_amdgcn_s_setprio(0);
    BAR();
#pragma unroll
    for (int n = 0; n < 2; n++) {
      b[n][0] = LDB_FRAG(p, 0, n, 0);
      b[n][1] = LDB_FRAG(p, 0, n, 1);
    }
    if (t + 2 < NT) {
      STAGE_A(t + 2, 0); STAGE_A(t + 2, 1);
      BAR();
      __builtin_amdgcn_s_setprio(1);
      mfma_quad<1, 0>(acc, a, b);
      __builtin_amdgcn_s_setprio(0);
      asm volatile("s_waitcnt vmcnt(4)" ::: "memory");
      BAR();
    } else {
      BAR();
      __builtin_amdgcn_s_setprio(1);
      mfma_quad<1, 0>(acc, a, b);
      __builtin_amdgcn_s_setprio(0);
      asm volatile("s_waitcnt vmcnt(0)" ::: "memory");
      BAR();
    }
  }

  float* os = So + (size_t)z * bsC;
#pragma unroll
  for (int n4 = 0; n4 < 4; n4++) {
    int col = bn + wc * 64 + n4 * 16 + rlo;
#pragma unroll
    for (int mi = 0; mi < 8; mi++) {
      int rowb = bm + wr * 128 + mi * 16 + (l >> 4) * 4;
#pragma unroll
      for (int r = 0; r < 4; r++) {
        int row = rowb + r;
        float v = acc[mi][n4][r] * 0.03125f;  // 1/sqrt(1024)
        if (col > row) v = -1e30f;
        os[(size_t)row * T_SEQ + col] = v;
      }
    }
  }
#undef ABUF
#undef BBUF
#undef STAGE_A
#undef STAGE_B
#undef LDA_FRAG
#undef LDB_FRAG
}

// ======== PV: 128x128 paired-triangular GEMM (34 BK-steps/WG, 1 round) =====
__global__ __launch_bounds__(512, 2) void pv_kernel(
    const __bf16* __restrict__ Ap, const __bf16* __restrict__ Btp,
    __bf16* __restrict__ Op, size_t bsA, size_t bsB, size_t bsC) {
  __shared__ __align__(16) char lds[98304];
#define ABUF(p3) (lds + (p3) * 16384)
#define BBUF(p3) (lds + 49152 + (p3) * 16384)

  const int tid = threadIdx.x;
  const int w = tid >> 6, l = tid & 63;
  const int wr = w >> 2, wc = w & 3;  // 2M x 4N; wave tile 64x32
  const int pid = (int)blockIdx.x >> 3;
  const int bn = ((int)blockIdx.x & 7) * 128;
  const int z = blockIdx.z;
  const __bf16* A = Ap + (size_t)z * bsA;
  const __bf16* Bt = Btp + (size_t)z * bsB;
  __bf16* O = Op + (size_t)z * bsC;

  const int grow = w * 16 + (l >> 2);
  const int cswz = (l & 3) ^ ((l >> 3) & 3);
  const int rlo = l & 15;
  const int xsw = (((l >> 4) ^ ((l >> 1) & 3)) << 4);

#define PSTAGE_A(t, p3)                                                      \
  {                                                                          \
    const __bf16* g = A + (size_t)(bm + grow) * 4096 + (t) * 64 + cswz * 8;  \
    char* d = ABUF(p3) + w * 1024 + l * 16;                                  \
    gload_lds16(g, d);                                                       \
    gload_lds16(g + 32, d + 8192);                                           \
  }
#define PSTAGE_B(t, p3)                                                      \
  {                                                                          \
    const __bf16* g = Bt + (size_t)(bn + grow) * 2048 + (t) * 64 + cswz * 8; \
    char* d = BBUF(p3) + w * 1024 + l * 16;                                  \
    gload_lds16(g, d);                                                       \
    gload_lds16(g + 32, d + 8192);                                           \
  }
#define PLDA(p3, i, kk)                                           \
  (*(const bf16x8*)(ABUF(p3) + (kk) * 8192 +                      \
                    (wr * 64 + (i) * 16 + rlo) * 64 + xsw))
#define PLDB(p3, n, kk)                                           \
  (*(const bf16x8*)(BBUF(p3) + (kk) * 8192 +                      \
                    (wc * 32 + (n) * 16 + rlo) * 64 + xsw))

#pragma unroll
  for (int seg = 0; seg < 2; ++seg) {
    const int i = seg ? (15 - pid) : pid;
    const int bm = i * 128;
    const int NT = (i + 1) * 2;  // BK=64 steps over K=(i+1)*128
    f32x4 acc[4][2] = {};

    PSTAGE_A(0, 0); PSTAGE_B(0, 0);
    if (NT > 1) { PSTAGE_A(1, 1); PSTAGE_B(1, 1); }
    asm volatile("s_waitcnt vmcnt(4)" ::: "memory");
    BAR();

    int p = 0, pn2 = 2;
    for (int t = 0; t < NT; ++t) {
      bf16x8 af[4][2], bfv[2][2];
#pragma unroll
      for (int m = 0; m < 4; m++) {
        af[m][0] = PLDA(p, m, 0);
        af[m][1] = PLDA(p, m, 1);
      }
#pragma unroll
      for (int n = 0; n < 2; n++) {
        bfv[n][0] = PLDB(p, n, 0);
        bfv[n][1] = PLDB(p, n, 1);
      }
      if (t + 2 < NT) { PSTAGE_A(t + 2, pn2); PSTAGE_B(t + 2, pn2); }
      BAR();
      __builtin_amdgcn_s_setprio(1);
#pragma unroll
      for (int m = 0; m < 4; m++)
#pragma unroll
        for (int n = 0; n < 2; n++) {
          acc[m][n] = MFMA16(af[m][0], bfv[n][0], acc[m][n]);
          acc[m][n] = MFMA16(af[m][1], bfv[n][1], acc[m][n]);
        }
      __builtin_amdgcn_s_setprio(0);
      if (t + 2 < NT) asm volatile("s_waitcnt vmcnt(4)" ::: "memory");
      else asm volatile("s_waitcnt vmcnt(0)" ::: "memory");
      BAR();
      p = (p + 1 == 3) ? 0 : p + 1;
      pn2 = (pn2 + 1 == 3) ? 0 : pn2 + 1;
    }

#pragma unroll
    for (int n = 0; n < 2; n++) {
      int col = bn + wc * 32 + n * 16 + rlo;
#pragma unroll
      for (int m = 0; m < 4; m++) {
        int rowb = bm + wr * 64 + m * 16 + (l >> 4) * 4;
#pragma unroll
        for (int r = 0; r < 4; r++)
          O[(size_t)(rowb + r) * D_MOD + col] = (__bf16)acc[m][n][r];
      }
    }
    BAR();  // LDS safe before next segment restage
  }
#undef ABUF
#undef BBUF
#undef PSTAGE_A
#undef PSTAGE_B
#undef PLDA
#undef PLDB
}

// ============ 128x256 triple-buffer GEMM (out-proj, f32 out + bias) ========
__global__ __launch_bounds__(512, 2) void oproj_kernel(
    const __bf16* __restrict__ A, const __bf16* __restrict__ Bt,
    const float* __restrict__ b0, float* __restrict__ o0) {
  constexpr int NT = 16;
  __shared__ __align__(16) char lds[147456];
#define ABUF(p3) (lds + (p3) * 16384)
#define BBUF(p3) (lds + 49152 + (p3) * 32768)

  const int tid = threadIdx.x;
  const int w = tid >> 6, l = tid & 63;
  const int wr = w >> 2, wc = w & 3;
  const int cpx = gridDim.x >> 3;
  const int swz = ((int)blockIdx.x & 7) * cpx + ((int)blockIdx.x >> 3);
  const int bm = (swz >> 2) * 128, bn = (swz & 3) * 256;

  const int grow = w * 16 + (l >> 2);
  const int cswz = (l & 3) ^ ((l >> 3) & 3);
  const int rlo = l & 15;
  const int xsw = (((l >> 4) ^ ((l >> 1) & 3)) << 4);

#define STAGE_A(t, p3)                                                       \
  {                                                                          \
    const __bf16* g = A + (size_t)(bm + grow) * 1024 + (t) * 64 + cswz * 8;  \
    char* d = ABUF(p3) + w * 1024 + l * 16;                                  \
    gload_lds16(g, d);                                                       \
    gload_lds16(g + 32, d + 8192);                                           \
  }
#define STAGE_B(t, p3)                                                       \
  {                                                                          \
    const __bf16* g = Bt + (size_t)(bn + grow) * 1024 + (t) * 64 + cswz * 8; \
    char* d = BBUF(p3) + w * 1024 + l * 16;                                  \
    gload_lds16(g, d);                                                       \
    gload_lds16(g + 32, d + 16384);                                          \
    const __bf16* g2 = g + (size_t)128 * 1024;                               \
    gload_lds16(g2, d + 8192);                                               \
    gload_lds16(g2 + 32, d + 8192 + 16384);                                  \
  }
#define LDA_FRAG(p3, i, kk)                                       \
  (*(const bf16x8*)(ABUF(p3) + (kk) * 8192 +                      \
                    (wr * 64 + (i) * 16 + rlo) * 64 + xsw))
#define LDB_FRAG(p3, n, kk)                                       \
  (*(const bf16x8*)(BBUF(p3) + (kk) * 16384 +                     \
                    (wc * 64 + (n) * 16 + rlo) * 64 + xsw))

  f32x4 acc[4][4] = {};
  STAGE_A(0, 0); STAGE_B(0, 0);
  STAGE_A(1, 1); STAGE_B(1, 1);
  asm volatile("s_waitcnt vmcnt(6)" ::: "memory");
  BAR();

  int p = 0, pn2 = 2;
  for (int t = 0; t < NT; ++t) {
    bf16x8 af[4][2], bf01[2][2], bf23[2][2];
#pragma unroll
    for (int i = 0; i < 4; i++) {
      af[i][0] = LDA_FRAG(p, i, 0);
      af[i][1] = LDA_FRAG(p, i, 1);
    }
#pragma unroll
    for (int n = 0; n < 2; n++) {
      bf01[n][0] = LDB_FRAG(p, n, 0);
      bf01[n][1] = LDB_FRAG(p, n, 1);
    }
    if (t + 2 < NT) STAGE_A(t + 2, pn2);
    BAR();
    __builtin_amdgcn_s_setprio(1);
#pragma unroll
    for (int i = 0; i < 4; i++)
#pragma unroll
      for (int n = 0; n < 2; n++) {
        acc[i][n] = MFMA16(af[i][0], bf01[n][0], acc[i][n]);
        acc[i][n] = MFMA16(af[i][1], bf01[n][1], acc[i][n]);
      }
    __builtin_amdgcn_s_setprio(0);
    BAR();
#pragma unroll
    for (int n = 0; n < 2; n++) {
      bf23[n][0] = LDB_FRAG(p, n + 2, 0);
      bf23[n][1] = LDB_FRAG(p, n + 2, 1);
    }
    if (t + 2 < NT) STAGE_B(t + 2, pn2);
    BAR();
    __builtin_amdgcn_s_setprio(1);
#pragma unroll
    for (int i = 0; i < 4; i++)
#pragma unroll
      for (int n = 0; n < 2; n++) {
        acc[i][n + 2] = MFMA16(af[i][0], bf23[n][0], acc[i][n + 2]);
        acc[i][n + 2] = MFMA16(af[i][1], bf23[n][1], acc[i][n + 2]);
      }
    __builtin_amdgcn_s_setprio(0);
    if (t + 2 < NT) {
      asm volatile("s_waitcnt vmcnt(6)" ::: "memory");
    } else {
      asm volatile("s_waitcnt vmcnt(0)" ::: "memory");
    }
    BAR();
    p = (p + 1 == 3) ? 0 : p + 1;
    pn2 = (pn2 + 1 == 3) ? 0 : pn2 + 1;
  }

#pragma unroll
  for (int n = 0; n < 4; n++) {
    int col = bn + wc * 64 + n * 16 + rlo;
    float bvv = b0[col];
#pragma unroll
    for (int m = 0; m < 4; m++) {
      int rowb = bm + wr * 64 + m * 16 + (l >> 4) * 4;
#pragma unroll
      for (int r = 0; r < 4; r++)
        o0[(size_t)(rowb + r) * D_MOD + col] = acc[m][n][r] + bvv;
    }
  }
#undef ABUF
#undef BBUF
#undef STAGE_A
#undef STAGE_B
#undef LDA_FRAG
#undef LDB_FRAG
}

// ----------------------- row softmax, P bf16 in-place ----------------------
__global__ __launch_bounds__(256) void softmax_kernel(float* __restrict__ S,
                                                      size_t bstride) {
  const int t = blockIdx.x, b = blockIdx.y;
  float* Srow = S + (size_t)b * bstride + (size_t)t * T_SEQ;
  __bf16* Prow = (__bf16*)Srow;
  const int L = ((t + 1) + 127) & ~127;
  const int tid = threadIdx.x;
  const int base = tid * 8;
  const bool act = base < L;
  float v[8];
  float m = -1e30f;
  if (act) {
    float4 a = *(const float4*)(Srow + base);
    float4 c = *(const float4*)(Srow + base + 4);
    v[0] = a.x; v[1] = a.y; v[2] = a.z; v[3] = a.w;
    v[4] = c.x; v[5] = c.y; v[6] = c.z; v[7] = c.w;
#pragma unroll
    for (int j = 0; j < 8; j++) m = fmaxf(m, v[j]);
  }
#pragma unroll
  for (int off = 1; off < 64; off <<= 1) m = fmaxf(m, __shfl_xor(m, off));
  __shared__ float redm[4], reds[4];
  const int wave = tid >> 6, lane = tid & 63;
  if (lane == 0) redm[wave] = m;
  __syncthreads();
  m = fmaxf(fmaxf(redm[0], redm[1]), fmaxf(redm[2], redm[3]));
  float p[8];
  float s = 0.f;
  if (act) {
#pragma unroll
    for (int j = 0; j < 8; j++) {
      p[j] = __expf(v[j] - m);
      s += p[j];
    }
  }
#pragma unroll
  for (int off = 1; off < 64; off <<= 1) s += __shfl_xor(s, off);
  if (lane == 0) reds[wave] = s;
  __syncthreads();  // fences: reads done before in-place bf16 writes
  const float inv = 1.0f / (reds[0] + reds[1] + reds[2] + reds[3]);
  if (act) {
    bf16x8 o;
#pragma unroll
    for (int j = 0; j < 8; j++) o[j] = (__bf16)(p[j] * inv);
    *(bf16x8*)(Prow + base) = o;
  }
}

// ---------------------------------------------------------------------------
extern "C" void kernel_launch(void* const* d_in, const int* in_sizes, int n_in,
                              void* d_out, int out_size, void* d_ws,
                              size_t ws_size, hipStream_t stream) {
  const float* x = (const float*)d_in[0];
  const float* Wq = (const float*)d_in[1];
  const float* bq = (const float*)d_in[2];
  const float* Wk = (const float*)d_in[3];
  const float* bk = (const float*)d_in[4];
  const float* Wv = (const float*)d_in[5];
  const float* bv = (const float*)d_in[6];
  const float* Wo = (const float*)d_in[7];
  const float* bo = (const float*)d_in[8];

  char* ws = (char*)d_ws;
  const size_t MB = 1u << 20;
  const size_t TC = (size_t)T_SEQ * D_MOD;  // 2M elems / batch
  const size_t TT = (size_t)T_SEQ * T_SEQ;  // 4M elems / batch
  __bf16* xb    = (__bf16*)(ws);            // [0,16) MB ; dead after QKV
  __bf16* Wqkvt = (__bf16*)(ws + 16 * MB);  // [16,22)  3072x1024
  __bf16* Wot   = (__bf16*)(ws + 22 * MB);  // [22,24)
  __bf16* Qb    = (__bf16*)(ws + 24 * MB);  // [24,40) ; later AO
  __bf16* Kb    = (__bf16*)(ws + 40 * MB);  // [40,56)
  __bf16* Vtb   = (__bf16*)(ws + 56 * MB);  // [56,72)  V^T direct from QKV

  // 1) prep: x -> bf16 + all 4 weight transposes, single dispatch
  prep_kernel<<<8192, 256, 0, stream>>>(x, Wq, Wk, Wv, Wo, xb, Wqkvt, Wot);
  // 2) fused QKV projection (48KiB LDS, 2 WGs/CU); V written transposed
  qkv256_kernel<<<768, 512, 0, stream>>>(xb, Wqkvt, bq, bk, bv, Qb, Kb, Vtb);

  const bool batched = ws_size >= 137 * MB;
  if (batched) {
    float* S = (float*)(ws + 72 * MB);  // [72,136) fp32, 4 batches
    __bf16* AO = Qb;                    // Q dead after QK
    // 3) S = QK^T * scale, causal: live 256^2 tiles only (36 per batch)
    qk_kernel<<<dim3(36, 1, 4), 512, 0, stream>>>(Qb, Kb, S, TC, TC, TT);
    // 4) row softmax, P bf16 in-place (row stride 4096 bf16)
    softmax_kernel<<<dim3(T_SEQ, 4), 256, 0, stream>>>(S, TT);
    // 5) O = P V, paired triangular 128x128 tiles (1 balanced round)
    pv_kernel<<<dim3(64, 1, 4), 512, 0, stream>>>((const __bf16*)S, Vtb, AO,
                                                  TT * 2, TC, TC);
    // 6) out projection (f32 out)
    oproj_kernel<<<256, 512, 0, stream>>>(AO, Wot, bo, (float*)d_out);
  } else {
    // per-batch fallback: S reuses xb region (dead after QKV), AO over Qb
    float* S = (float*)(ws);
    __bf16* AO = Qb;
    for (int b = 0; b < 4; ++b) {
      qk_kernel<<<dim3(36, 1, 1), 512, 0, stream>>>(Qb + b * TC, Kb + b * TC,
                                                    S, 0, 0, 0);
      softmax_kernel<<<dim3(T_SEQ, 1), 256, 0, stream>>>(S, 0);
      pv_kernel<<<dim3(64, 1, 1), 512, 0, stream>>>(
          (const __bf16*)S, Vtb + b * TC, AO + b * TC, 0, 0, 0);
    }
    oproj_kernel<<<256, 512, 0, stream>>>(AO, Wot, bo, (float*)d_out);
  }
}